// Round 2
// baseline (130815.979 us; speedup 1.0000x reference)
//
#include <hip/hip_runtime.h>
#include <math.h>

// BatchFrechetMean: inductive geodesic mean of 256 SPD 256x256 matrices.
// Eigh-free: fixed-interval Chebyshev polynomial evaluation of M^{-1/2} and S^t,
// executed as a persistent kernel (plain launch, 64 blocks <= 256 CUs so all
// blocks are co-resident) with a hand-rolled agent-scope grid barrier.
//
// Spectral bounds (provable): lambda(f) in [1, ~5.3] => lambda(M) in [1, ~5.3],
// lambda(S) in [~0.18, ~5.5]. Approximation intervals with margin:
//   x^{-1/2} on [0.80, 6.50], degree 15 (s=4, m=3)  -> err ~1e-4
//   x^{t}    on [0.12, 6.50], degree 47 (s=8, m=5)  -> err ~1e-4

#define NBLK 64
#define AM 0.80f
#define BM 6.50f
#define AS_ 0.12f
#define BS_ 6.50f

typedef __attribute__((ext_vector_type(8))) short bf16x8;
typedef __attribute__((ext_vector_type(4))) float f32x4;

enum {
  iXM = 0, iU2, iU3, iU4, iCBA, iCBB, iCBC, iISQ, iSQ, iG,
  iXS, iV2, iV3, iV4, iV5, iV6, iV7, iV8, iSBA, iSBB, iSBC, iPP, iHH,
  NBUF
};

__device__ __align__(16) float gB[NBUF][65536];   // 23 * 256KB = ~5.9 MB scratch
__device__ float g_aS[256][48];                   // per-step regrouped Cheb coeffs of x^{t_k}
__device__ float g_aM[16];                        // regrouped Cheb coeffs of x^{-1/2}
__device__ int g_c0[8];
__device__ int g_c1;
__device__ int g_gen;

__device__ __forceinline__ short f2bf(float x) {
  unsigned u = __builtin_bit_cast(unsigned, x);
  unsigned r = (u + 0x7FFFu + ((u >> 16) & 1u)) >> 16;   // RNE to bf16
  return (short)(unsigned short)r;
}
__device__ __forceinline__ float bf2f(short h) {
  unsigned u = ((unsigned)(unsigned short)h) << 16;
  return __builtin_bit_cast(float, u);
}

// Raw 256^3 matmul fragment: this thread's 4 accumulator values of A*B.
// Split-bf16 (hi+lo) -> ~1e-5 relative error, 3 MFMAs per K-chunk.
__device__ __forceinline__ f32x4 mmraw(const float* __restrict__ A,
                                       const float* __restrict__ B,
                                       int aoff, int boff) {
  f32x4 acc = {0.0f, 0.0f, 0.0f, 0.0f};
  const float* ap = A + aoff;
  const float* bp = B + boff;
#pragma unroll
  for (int k0 = 0; k0 < 256; k0 += 32) {
    float av[8], bv[8];
    float4 a0 = *(const float4*)(ap + k0);
    float4 a1 = *(const float4*)(ap + k0 + 4);
    av[0] = a0.x; av[1] = a0.y; av[2] = a0.z; av[3] = a0.w;
    av[4] = a1.x; av[5] = a1.y; av[6] = a1.z; av[7] = a1.w;
#pragma unroll
    for (int j = 0; j < 8; j++) bv[j] = bp[(k0 + j) * 256];
    bf16x8 ah, am, bh, bm;
#pragma unroll
    for (int j = 0; j < 8; j++) {
      short h = f2bf(av[j]);
      ah[j] = h;
      am[j] = f2bf(av[j] - bf2f(h));
      short g = f2bf(bv[j]);
      bh[j] = g;
      bm[j] = f2bf(bv[j] - bf2f(g));
    }
    acc = __builtin_amdgcn_mfma_f32_16x16x32_bf16(ah, bh, acc, 0, 0, 0);
    acc = __builtin_amdgcn_mfma_f32_16x16x32_bf16(am, bh, acc, 0, 0, 0);
    acc = __builtin_amdgcn_mfma_f32_16x16x32_bf16(ah, bm, acc, 0, 0, 0);
  }
  return acc;
}

struct Combo {
  float alpha, gI;
  int ne;
  const float* E[8];
  float g[8];
};

// C[idx] = alpha*acc + sum_e g[e]*E[e][idx] + gI*(row==col)
__device__ __forceinline__ void epi_store(float* __restrict__ C, const f32x4 acc,
                                          const Combo& cb, int row0, int colg) {
#pragma unroll
  for (int r = 0; r < 4; r++) {
    int row = row0 + r;
    int idx = row * 256 + colg;
    float v = cb.alpha * acc[r];
    for (int e = 0; e < cb.ne; e++) v += cb.g[e] * cb.E[e][idx];
    if (row == colg) v += cb.gI;
    C[idx] = v;
  }
}

// Two-level grid barrier (8 groups of 8, group = bid&7 ~ XCD under round-robin).
__device__ __forceinline__ void gridbar(int bid, int* sgen) {
  __syncthreads();
  if (threadIdx.x == 0) {
    int g = *sgen;
    int grp = bid & 7;
    int v = __hip_atomic_fetch_add(&g_c0[grp], 1, __ATOMIC_ACQ_REL, __HIP_MEMORY_SCOPE_AGENT);
    if (v == NBLK / 8 - 1) {
      __hip_atomic_store(&g_c0[grp], 0, __ATOMIC_RELAXED, __HIP_MEMORY_SCOPE_AGENT);
      int w = __hip_atomic_fetch_add(&g_c1, 1, __ATOMIC_ACQ_REL, __HIP_MEMORY_SCOPE_AGENT);
      if (w == 7) {
        __hip_atomic_store(&g_c1, 0, __ATOMIC_RELAXED, __HIP_MEMORY_SCOPE_AGENT);
        __hip_atomic_store(&g_gen, g + 1, __ATOMIC_RELEASE, __HIP_MEMORY_SCOPE_AGENT);
      } else {
        while (__hip_atomic_load(&g_gen, __ATOMIC_ACQUIRE, __HIP_MEMORY_SCOPE_AGENT) <= g)
          __builtin_amdgcn_s_sleep(2);
      }
    } else {
      while (__hip_atomic_load(&g_gen, __ATOMIC_ACQUIRE, __HIP_MEMORY_SCOPE_AGENT) <= g)
        __builtin_amdgcn_s_sleep(2);
    }
    *sgen = g + 1;
  }
  __syncthreads();
}

// Chebyshev-PS regrouping: p = sum_j c_j T_j  ->  sum_i (sum_r a[i][r] T_r(x)) T_i(T_s(x))
// a[i][r] = 2c[is+r] - a[i+1][s-r] (a[i][0]=c[is]); a[0][r] = c[r] - 0.5 a[1][s-r]; a[0][0]=c[0].
__device__ void regroup_d(const double* c, float* outp, int s, int m) {
  double al[64];
  for (int i = m; i >= 1; i--)
    for (int r = 0; r < s; r++) {
      double v;
      if (r == 0) v = c[s * i];
      else v = 2.0 * c[s * i + r] - ((i == m) ? 0.0 : al[s * (i + 1) + (s - r)]);
      al[s * i + r] = v;
    }
  al[0] = c[0];
  for (int r = 1; r < s; r++) al[r] = c[r] - 0.5 * al[s + (s - r)];
  int tot = s * (m + 1);
  for (int j = 0; j < tot; j++) outp[j] = (float)al[j];
}

// Setup: per-step Chebyshev coefficients (128-node DCT in fp64) + barrier reset.
__global__ void setup_kernel(const float* __restrict__ wts) {
  const int k = blockIdx.x;
  const int lane = threadIdx.x;
  __shared__ double s_fv[128];
  __shared__ double s_c[64];
  const double PI = 3.14159265358979323846;
  if (k < 256) {
    double w0 = (double)wts[2 * k], w1 = (double)wts[2 * k + 1];
    double t = 1.0 / (1.0 + exp(w0 - w1));     // softmax(...)[ ,1]
    double c0 = 0.5 * ((double)AS_ + (double)BS_), h0 = 0.5 * ((double)BS_ - (double)AS_);
    for (int i = lane; i < 128; i += 64) {
      double th = (i + 0.5) * PI / 128.0;
      double y = c0 + h0 * cos(th);
      s_fv[i] = pow(y, t);
    }
    __syncthreads();
    if (lane < 48) {
      double s = 0.0;
      for (int i = 0; i < 128; i++) {
        double th = (i + 0.5) * PI / 128.0;
        s += s_fv[i] * cos((double)lane * th);
      }
      s_c[lane] = s * ((lane == 0) ? 1.0 : 2.0) / 128.0;
    }
    __syncthreads();
    if (lane == 0) regroup_d(s_c, g_aS[k], 8, 5);
  } else {
    double c0 = 0.5 * ((double)AM + (double)BM), h0 = 0.5 * ((double)BM - (double)AM);
    for (int i = lane; i < 128; i += 64) {
      double th = (i + 0.5) * PI / 128.0;
      double y = c0 + h0 * cos(th);
      s_fv[i] = 1.0 / sqrt(y);
    }
    __syncthreads();
    if (lane < 16) {
      double s = 0.0;
      for (int i = 0; i < 128; i++) {
        double th = (i + 0.5) * PI / 128.0;
        s += s_fv[i] * cos((double)lane * th);
      }
      s_c[lane] = s * ((lane == 0) ? 1.0 : 2.0) / 128.0;
    }
    __syncthreads();
    if (lane == 0) {
      regroup_d(s_c, g_aM, 4, 3);
      g_c1 = 0; g_gen = 0;
      for (int j = 0; j < 8; j++) g_c0[j] = 0;
    }
  }
}

// Clenshaw round helper (outer series in w = V8): dst = alpha*(V8*bop) + q + (-sub)
__device__ __forceinline__ void cheb_round(int dst, int bop, const float* q, int sub,
                                           float alpha, int aoff, int boff, int row0, int colg) {
  f32x4 a = mmraw(gB[iV8], gB[bop], aoff, boff);
  Combo cb;
  cb.alpha = alpha; cb.gI = q[0]; cb.ne = (sub >= 0) ? 8 : 7;
  cb.E[0] = gB[iXS]; cb.g[0] = q[1];
  cb.E[1] = gB[iV2]; cb.g[1] = q[2];
  cb.E[2] = gB[iV3]; cb.g[2] = q[3];
  cb.E[3] = gB[iV4]; cb.g[3] = q[4];
  cb.E[4] = gB[iV5]; cb.g[4] = q[5];
  cb.E[5] = gB[iV6]; cb.g[5] = q[6];
  cb.E[6] = gB[iV7]; cb.g[6] = q[7];
  if (sub >= 0) { cb.E[7] = gB[sub]; cb.g[7] = -1.0f; }
  epi_store(gB[dst], a, cb, row0, colg);
}

__global__ void __launch_bounds__(256) frechet_kernel(const float* __restrict__ f,
                                                      float* __restrict__ out) {
  __shared__ int s_gen;
  const int tid = threadIdx.x, bid = blockIdx.x;
  const int lane = tid & 63, wave = tid >> 6;
  const int tr = (bid >> 3) * 32, tc = (bid & 7) * 32;
  const int sr = (wave >> 1) * 16, sc = (wave & 1) * 16;
  const int arow = tr + sr + (lane & 15);
  const int colg = tc + sc + (lane & 15);
  const int kq = (lane >> 4) * 8;
  const int row0 = tr + sr + (lane >> 4) * 4;
  const int aoff = arow * 256 + kq;
  const int boff = kq * 256 + colg;
  if (tid == 0) s_gen = 0;
  __syncthreads();

  const float sM = 2.0f / (BM - AM), cM = 0.5f * (AM + BM);
  const float sS = 2.0f / (BS_ - AS_), cS = 0.5f * (AS_ + BS_);

  // M0 = I  ->  XM = sM*(I - cM*I)
  for (int i = bid * 256 + tid; i < 65536; i += NBLK * 256)
    gB[iXM][i] = ((i >> 8) == (i & 255)) ? sM * (1.0f - cM) : 0.0f;
  gridbar(bid, &s_gen);

  for (int k = 0; k < 256; k++) {
    const float* fk = f + (size_t)k * 65536;
    const float* aS = g_aS[k];
    const float* aM = g_aM;
    Combo cb;

    // ---- isq = p(M) ~ M^{-1/2}: inner T-chain + Clenshaw (s=4, m=3) ----
    { // r1: U2 = 2*XM*XM - I
      f32x4 a = mmraw(gB[iXM], gB[iXM], aoff, boff);
      cb.alpha = 2.0f; cb.gI = -1.0f; cb.ne = 0;
      epi_store(gB[iU2], a, cb, row0, colg);
    }
    gridbar(bid, &s_gen);
    { // r2: U3 = 2*XM*U2 - XM ; U4 = 2*U2*U2 - I ; CBA = qM3 (same-round vals from regs)
      f32x4 a3 = mmraw(gB[iXM], gB[iU2], aoff, boff);
      f32x4 a4 = mmraw(gB[iU2], gB[iU2], aoff, boff);
#pragma unroll
      for (int r = 0; r < 4; r++) {
        int row = row0 + r, idx = row * 256 + colg;
        float dI = (row == colg) ? 1.0f : 0.0f;
        float xm = gB[iXM][idx], u2 = gB[iU2][idx];
        float u3 = 2.0f * a3[r] - xm;
        gB[iU3][idx] = u3;
        gB[iU4][idx] = 2.0f * a4[r] - dI;
        gB[iCBA][idx] = aM[12] * dI + aM[13] * xm + aM[14] * u2 + aM[15] * u3;
      }
    }
    gridbar(bid, &s_gen);
    { // r3: CBB = 2*U4*CBA + qM2
      f32x4 a = mmraw(gB[iU4], gB[iCBA], aoff, boff);
      cb.alpha = 2.0f; cb.gI = aM[8]; cb.ne = 3;
      cb.E[0] = gB[iXM]; cb.g[0] = aM[9];
      cb.E[1] = gB[iU2]; cb.g[1] = aM[10];
      cb.E[2] = gB[iU3]; cb.g[2] = aM[11];
      epi_store(gB[iCBB], a, cb, row0, colg);
    }
    gridbar(bid, &s_gen);
    { // r4: CBC = 2*U4*CBB - CBA + qM1
      f32x4 a = mmraw(gB[iU4], gB[iCBB], aoff, boff);
      cb.alpha = 2.0f; cb.gI = aM[4]; cb.ne = 4;
      cb.E[0] = gB[iXM]; cb.g[0] = aM[5];
      cb.E[1] = gB[iU2]; cb.g[1] = aM[6];
      cb.E[2] = gB[iU3]; cb.g[2] = aM[7];
      cb.E[3] = gB[iCBA]; cb.g[3] = -1.0f;
      epi_store(gB[iCBC], a, cb, row0, colg);
    }
    gridbar(bid, &s_gen);
    { // r5: ISQ = U4*CBC - CBB + qM0
      f32x4 a = mmraw(gB[iU4], gB[iCBC], aoff, boff);
      cb.alpha = 1.0f; cb.gI = aM[0]; cb.ne = 4;
      cb.E[0] = gB[iXM]; cb.g[0] = aM[1];
      cb.E[1] = gB[iU2]; cb.g[1] = aM[2];
      cb.E[2] = gB[iU3]; cb.g[2] = aM[3];
      cb.E[3] = gB[iCBB]; cb.g[3] = -1.0f;
      epi_store(gB[iISQ], a, cb, row0, colg);
    }
    gridbar(bid, &s_gen);
    { // r6: SQ = M*ISQ = (1/sM)*XM*ISQ + cM*ISQ ; G = ISQ*fk
      f32x4 a = mmraw(gB[iXM], gB[iISQ], aoff, boff);
      cb.alpha = 1.0f / sM; cb.gI = 0.0f; cb.ne = 1;
      cb.E[0] = gB[iISQ]; cb.g[0] = cM;
      epi_store(gB[iSQ], a, cb, row0, colg);
      f32x4 b = mmraw(gB[iISQ], fk, aoff, boff);
      cb.alpha = 1.0f; cb.gI = 0.0f; cb.ne = 0;
      epi_store(gB[iG], b, cb, row0, colg);
    }
    gridbar(bid, &s_gen);
    { // r7: XS = sS*(G*ISQ) - sS*cS*I  (scaled S)
      f32x4 a = mmraw(gB[iG], gB[iISQ], aoff, boff);
      cb.alpha = sS; cb.gI = -sS * cS; cb.ne = 0;
      epi_store(gB[iXS], a, cb, row0, colg);
    }
    gridbar(bid, &s_gen);

    // ---- P = p(S) ~ S^t: inner T2..T8 + Clenshaw (s=8, m=5, d=47) ----
    { // r8: V2 = 2*XS*XS - I
      f32x4 a = mmraw(gB[iXS], gB[iXS], aoff, boff);
      cb.alpha = 2.0f; cb.gI = -1.0f; cb.ne = 0;
      epi_store(gB[iV2], a, cb, row0, colg);
    }
    gridbar(bid, &s_gen);
    { // r9: V3 = 2*XS*V2 - XS ; V4 = 2*V2*V2 - I
      f32x4 a = mmraw(gB[iXS], gB[iV2], aoff, boff);
      cb.alpha = 2.0f; cb.gI = 0.0f; cb.ne = 1; cb.E[0] = gB[iXS]; cb.g[0] = -1.0f;
      epi_store(gB[iV3], a, cb, row0, colg);
      f32x4 b = mmraw(gB[iV2], gB[iV2], aoff, boff);
      cb.alpha = 2.0f; cb.gI = -1.0f; cb.ne = 0;
      epi_store(gB[iV4], b, cb, row0, colg);
    }
    gridbar(bid, &s_gen);
    { // r10: V5,V6,V7,V8 + SBA = q5 (b_m). Same-round V5..V7 kept in registers.
      f32x4 a5 = mmraw(gB[iV2], gB[iV3], aoff, boff);
      f32x4 a6 = mmraw(gB[iV3], gB[iV3], aoff, boff);
      f32x4 a7 = mmraw(gB[iV3], gB[iV4], aoff, boff);
      f32x4 a8 = mmraw(gB[iV4], gB[iV4], aoff, boff);
#pragma unroll
      for (int r = 0; r < 4; r++) {
        int row = row0 + r, idx = row * 256 + colg;
        float dI = (row == colg) ? 1.0f : 0.0f;
        float xs = gB[iXS][idx], v2 = gB[iV2][idx], v3 = gB[iV3][idx], v4 = gB[iV4][idx];
        float v5 = 2.0f * a5[r] - xs;
        float v6 = 2.0f * a6[r] - dI;
        float v7 = 2.0f * a7[r] - xs;
        float v8 = 2.0f * a8[r] - dI;
        gB[iV5][idx] = v5; gB[iV6][idx] = v6; gB[iV7][idx] = v7; gB[iV8][idx] = v8;
        gB[iSBA][idx] = aS[40] * dI + aS[41] * xs + aS[42] * v2 + aS[43] * v3 +
                        aS[44] * v4 + aS[45] * v5 + aS[46] * v6 + aS[47] * v7;
      }
    }
    gridbar(bid, &s_gen);
    cheb_round(iSBB, iSBA, aS + 32, -1,  2.0f, aoff, boff, row0, colg);  // b4
    gridbar(bid, &s_gen);
    cheb_round(iSBC, iSBB, aS + 24, iSBA, 2.0f, aoff, boff, row0, colg); // b3
    gridbar(bid, &s_gen);
    cheb_round(iSBA, iSBC, aS + 16, iSBB, 2.0f, aoff, boff, row0, colg); // b2
    gridbar(bid, &s_gen);
    cheb_round(iSBB, iSBA, aS + 8,  iSBC, 2.0f, aoff, boff, row0, colg); // b1
    gridbar(bid, &s_gen);
    cheb_round(iPP,  iSBB, aS + 0,  iSBA, 1.0f, aoff, boff, row0, colg); // P
    gridbar(bid, &s_gen);

    { // r16: HH = SQ*P
      f32x4 a = mmraw(gB[iSQ], gB[iPP], aoff, boff);
      cb.alpha = 1.0f; cb.gI = 0.0f; cb.ne = 0;
      epi_store(gB[iHH], a, cb, row0, colg);
    }
    gridbar(bid, &s_gen);
    { // r17: Mn = HH*SQ -> out[k]; XM_next = sM*(Mn - cM*I)
      f32x4 a = mmraw(gB[iHH], gB[iSQ], aoff, boff);
      float* ok = out + (size_t)k * 65536;
#pragma unroll
      for (int r = 0; r < 4; r++) {
        int row = row0 + r, idx = row * 256 + colg;
        float dI = (row == colg) ? 1.0f : 0.0f;
        float v = a[r];
        ok[idx] = v;
        gB[iXM][idx] = sM * (v - cM * dI);
      }
    }
    gridbar(bid, &s_gen);
  }
}

extern "C" void kernel_launch(void* const* d_in, const int* in_sizes, int n_in,
                              void* d_out, int out_size, void* d_ws, size_t ws_size,
                              hipStream_t stream) {
  (void)in_sizes; (void)n_in; (void)d_ws; (void)ws_size; (void)out_size;
  const float* f = (const float*)d_in[0];
  const float* w = (const float*)d_in[1];
  float* out = (float*)d_out;

  setup_kernel<<<dim3(257), dim3(64), 0, stream>>>(w);

  // Plain (non-cooperative) launch: 64 blocks x 256 threads on 256 CUs is
  // trivially co-resident, so the hand-rolled agent-scope barrier is safe.
  frechet_kernel<<<dim3(NBLK), dim3(256), 0, stream>>>(f, out);
}

// Round 3
// 60071.130 us; speedup vs baseline: 2.1777x; 2.1777x over previous
//
#include <hip/hip_runtime.h>
#include <math.h>

// BatchFrechetMean: inductive geodesic mean of 256 SPD 256x256 matrices.
// Eigh-free: fixed-interval Chebyshev polynomial evaluation of M^{-1/2} and S^t,
// persistent kernel (64 blocks, plain launch, co-resident) + hand-rolled
// agent-scope grid barrier. R3: symmetric-B row reads (all B operands are
// symmetric), bf16 hi/lo plane storage (no per-use cvt VALU, dwordx4 loads),
// deg 11 / deg 39 polys with Q-precompute: 15 rounds, 21 matmuls per step.
//
// Spectral bounds (provable): lambda(f) in [1, ~5.2] => lambda(M) in [1, 5.5],
// lambda(S) in [1/5.75, 5.75]. Approximation intervals with margin:
//   x^{-1/2} on [0.95, 5.75], deg 11 (s=4, m=2)  -> err ~5e-5
//   x^{t}    on [0.17, 5.90], deg 39 (s=8, m=4)  -> err ~3e-5

#define NBLK 64
#define AM 0.95f
#define BM 5.75f
#define AS_ 0.17f
#define BS_ 5.90f

typedef __attribute__((ext_vector_type(8))) short bf16x8;
typedef __attribute__((ext_vector_type(4))) float f32x4;

enum {
  iXM = 0, iU2, iU4, iCBA, iCBB, iQM1, iQM0, iISQ, iSQ, iG,
  iXS, iV2, iV3, iV4, iV8, iSBA, iSBB, iSBC, iQS3, iQS2, iQS1, iQS0, iPP, iHH,
  NBUF
};

// Matrices stored as bf16 hi+lo planes (value = hi + lo, ~2^-16 rel err).
__device__ __align__(16) short gHi[NBUF][65536];
__device__ __align__(16) short gLo[NBUF][65536];
__device__ float g_aS[256][40];   // per-step regrouped Cheb coeffs of x^{t_k}
__device__ float g_aM[12];        // regrouped Cheb coeffs of x^{-1/2}
__device__ int g_c0[8];
__device__ int g_c1;
__device__ int g_gen;

__device__ __forceinline__ short f2bf(float x) {
  unsigned u = __builtin_bit_cast(unsigned, x);
  unsigned r = (u + 0x7FFFu + ((u >> 16) & 1u)) >> 16;   // RNE to bf16
  return (short)(unsigned short)r;
}
__device__ __forceinline__ float bf2f(short h) {
  unsigned u = ((unsigned)(unsigned short)h) << 16;
  return __builtin_bit_cast(float, u);
}
__device__ __forceinline__ float rdm(int m, int idx) {
  return bf2f(gHi[m][idx]) + bf2f(gLo[m][idx]);
}
__device__ __forceinline__ void wrm(int m, int idx, float v) {
  short h = f2bf(v);
  gHi[m][idx] = h;
  gLo[m][idx] = f2bf(v - bf2f(h));
}

// C(arow, bcol) fragment of A*B; B symmetric -> read B by rows (dwordx4).
// Split hi/lo bf16: 3 MFMAs per K-chunk, ~1e-5 rel err per matmul.
__device__ __forceinline__ f32x4 mmbf(int Ai, int Bi, int arow, int bcol, int kq) {
  f32x4 acc = {0.0f, 0.0f, 0.0f, 0.0f};
  const short* ah = gHi[Ai] + arow * 256 + kq;
  const short* al = gLo[Ai] + arow * 256 + kq;
  const short* bh = gHi[Bi] + bcol * 256 + kq;
  const short* bl = gLo[Bi] + bcol * 256 + kq;
#pragma unroll
  for (int k0 = 0; k0 < 256; k0 += 32) {
    bf16x8 Ah = *(const bf16x8*)(ah + k0);
    bf16x8 Al = *(const bf16x8*)(al + k0);
    bf16x8 Bh = *(const bf16x8*)(bh + k0);
    bf16x8 Bl = *(const bf16x8*)(bl + k0);
    acc = __builtin_amdgcn_mfma_f32_16x16x32_bf16(Ah, Bh, acc, 0, 0, 0);
    acc = __builtin_amdgcn_mfma_f32_16x16x32_bf16(Al, Bh, acc, 0, 0, 0);
    acc = __builtin_amdgcn_mfma_f32_16x16x32_bf16(Ah, Bl, acc, 0, 0, 0);
  }
  return acc;
}

// Same but B is an fp32 symmetric matrix (the input f_k), converted in-loop.
__device__ __forceinline__ f32x4 mmbf_fB(int Ai, const float* __restrict__ B,
                                         int arow, int bcol, int kq) {
  f32x4 acc = {0.0f, 0.0f, 0.0f, 0.0f};
  const short* ah = gHi[Ai] + arow * 256 + kq;
  const short* al = gLo[Ai] + arow * 256 + kq;
  const float* bp = B + bcol * 256 + kq;
#pragma unroll
  for (int k0 = 0; k0 < 256; k0 += 32) {
    bf16x8 Ah = *(const bf16x8*)(ah + k0);
    bf16x8 Al = *(const bf16x8*)(al + k0);
    float4 b0 = *(const float4*)(bp + k0);
    float4 b1 = *(const float4*)(bp + k0 + 4);
    float bv[8] = {b0.x, b0.y, b0.z, b0.w, b1.x, b1.y, b1.z, b1.w};
    bf16x8 Bh, Bl;
#pragma unroll
    for (int j = 0; j < 8; j++) {
      short g = f2bf(bv[j]);
      Bh[j] = g;
      Bl[j] = f2bf(bv[j] - bf2f(g));
    }
    acc = __builtin_amdgcn_mfma_f32_16x16x32_bf16(Ah, Bh, acc, 0, 0, 0);
    acc = __builtin_amdgcn_mfma_f32_16x16x32_bf16(Al, Bh, acc, 0, 0, 0);
    acc = __builtin_amdgcn_mfma_f32_16x16x32_bf16(Ah, Bl, acc, 0, 0, 0);
  }
  return acc;
}

// Two-level grid barrier (8 groups of 8, group = bid&7 ~ XCD under round-robin).
__device__ __forceinline__ void gridbar(int bid, int* sgen) {
  __syncthreads();
  if (threadIdx.x == 0) {
    int g = *sgen;
    int grp = bid & 7;
    int v = __hip_atomic_fetch_add(&g_c0[grp], 1, __ATOMIC_ACQ_REL, __HIP_MEMORY_SCOPE_AGENT);
    if (v == NBLK / 8 - 1) {
      __hip_atomic_store(&g_c0[grp], 0, __ATOMIC_RELAXED, __HIP_MEMORY_SCOPE_AGENT);
      int w = __hip_atomic_fetch_add(&g_c1, 1, __ATOMIC_ACQ_REL, __HIP_MEMORY_SCOPE_AGENT);
      if (w == 7) {
        __hip_atomic_store(&g_c1, 0, __ATOMIC_RELAXED, __HIP_MEMORY_SCOPE_AGENT);
        __hip_atomic_store(&g_gen, g + 1, __ATOMIC_RELEASE, __HIP_MEMORY_SCOPE_AGENT);
      } else {
        while (__hip_atomic_load(&g_gen, __ATOMIC_ACQUIRE, __HIP_MEMORY_SCOPE_AGENT) <= g)
          __builtin_amdgcn_s_sleep(2);
      }
    } else {
      while (__hip_atomic_load(&g_gen, __ATOMIC_ACQUIRE, __HIP_MEMORY_SCOPE_AGENT) <= g)
        __builtin_amdgcn_s_sleep(2);
    }
    *sgen = g + 1;
  }
  __syncthreads();
}

// Chebyshev-PS regrouping: p = sum_j c_j T_j  ->  sum_i q_i(x) T_i(T_s(x)),
// q_i = sum_r a[i][r] T_r.  a[i][r] = 2c[is+r] - a[i+1][s-r] (a[i][0]=c[is]);
// a[0][r] = c[r] - 0.5 a[1][s-r]; a[0][0] = c[0].
__device__ void regroup_d(const double* c, float* outp, int s, int m) {
  double al[64];
  for (int i = m; i >= 1; i--)
    for (int r = 0; r < s; r++) {
      double v;
      if (r == 0) v = c[s * i];
      else v = 2.0 * c[s * i + r] - ((i == m) ? 0.0 : al[s * (i + 1) + (s - r)]);
      al[s * i + r] = v;
    }
  al[0] = c[0];
  for (int r = 1; r < s; r++) al[r] = c[r] - 0.5 * al[s + (s - r)];
  int tot = s * (m + 1);
  for (int j = 0; j < tot; j++) outp[j] = (float)al[j];
}

// Setup: per-step Chebyshev coefficients (128-node DCT in fp64) + barrier reset.
__global__ void setup_kernel(const float* __restrict__ wts) {
  const int k = blockIdx.x;
  const int lane = threadIdx.x;
  __shared__ double s_fv[128];
  __shared__ double s_c[64];
  const double PI = 3.14159265358979323846;
  if (k < 256) {
    double w0 = (double)wts[2 * k], w1 = (double)wts[2 * k + 1];
    double t = 1.0 / (1.0 + exp(w0 - w1));     // softmax(...)[:,1]
    double c0 = 0.5 * ((double)AS_ + (double)BS_), h0 = 0.5 * ((double)BS_ - (double)AS_);
    for (int i = lane; i < 128; i += 64) {
      double th = (i + 0.5) * PI / 128.0;
      double y = c0 + h0 * cos(th);
      s_fv[i] = pow(y, t);
    }
    __syncthreads();
    if (lane < 40) {
      double s = 0.0;
      for (int i = 0; i < 128; i++) {
        double th = (i + 0.5) * PI / 128.0;
        s += s_fv[i] * cos((double)lane * th);
      }
      s_c[lane] = s * ((lane == 0) ? 1.0 : 2.0) / 128.0;
    }
    __syncthreads();
    if (lane == 0) regroup_d(s_c, g_aS[k], 8, 4);
  } else {
    double c0 = 0.5 * ((double)AM + (double)BM), h0 = 0.5 * ((double)BM - (double)AM);
    for (int i = lane; i < 128; i += 64) {
      double th = (i + 0.5) * PI / 128.0;
      double y = c0 + h0 * cos(th);
      s_fv[i] = 1.0 / sqrt(y);
    }
    __syncthreads();
    if (lane < 12) {
      double s = 0.0;
      for (int i = 0; i < 128; i++) {
        double th = (i + 0.5) * PI / 128.0;
        s += s_fv[i] * cos((double)lane * th);
      }
      s_c[lane] = s * ((lane == 0) ? 1.0 : 2.0) / 128.0;
    }
    __syncthreads();
    if (lane == 0) {
      regroup_d(s_c, g_aM, 4, 2);
      g_c1 = 0; g_gen = 0;
      for (int j = 0; j < 8; j++) g_c0[j] = 0;
    }
  }
}

__global__ void __launch_bounds__(256) frechet_kernel(const float* __restrict__ f,
                                                      float* __restrict__ out) {
  __shared__ int s_gen;
  const int tid = threadIdx.x, bid = blockIdx.x;
  const int lane = tid & 63, wave = tid >> 6;
  const int tr = (bid >> 3) * 32, tc = (bid & 7) * 32;
  const int sr = (wave >> 1) * 16, sc = (wave & 1) * 16;
  const int arow = tr + sr + (lane & 15);     // A-fragment row (global)
  const int colg = tc + sc + (lane & 15);     // C col = B-sym row (global)
  const int kq = (lane >> 4) * 8;             // K sub-offset within chunk
  const int row0 = tr + sr + (lane >> 4) * 4; // C rows for acc[0..3]
  if (tid == 0) s_gen = 0;
  __syncthreads();

  const float sM = 2.0f / (BM - AM), cM = 0.5f * (AM + BM);
  const float sS = 2.0f / (BS_ - AS_), cS = 0.5f * (AS_ + BS_);

  // M0 = I  ->  XM = sM*(I - cM*I)
  for (int i = bid * 256 + tid; i < 65536; i += NBLK * 256)
    wrm(iXM, i, ((i >> 8) == (i & 255)) ? sM * (1.0f - cM) : 0.0f);
  gridbar(bid, &s_gen);

  for (int k = 0; k < 256; k++) {
    const float* fk = f + (size_t)k * 65536;
    const float* aS = g_aS[k];
    const float* aM = g_aM;

    // ---- ISQ = p(M) ~ M^{-1/2}: s=4, m=2, deg 11 ----
    { // r1: U2 = 2*XM*XM - I
      f32x4 a = mmbf(iXM, iXM, arow, colg, kq);
#pragma unroll
      for (int r = 0; r < 4; r++) {
        int row = row0 + r, idx = row * 256 + colg;
        wrm(iU2, idx, 2.0f * a[r] - ((row == colg) ? 1.0f : 0.0f));
      }
    }
    gridbar(bid, &s_gen);
    { // r2: U3 (regs), U4 ; precompute q2 (CBA), Q1, Q0 combos
      f32x4 a3 = mmbf(iXM, iU2, arow, colg, kq);
      f32x4 a4 = mmbf(iU2, iU2, arow, colg, kq);
#pragma unroll
      for (int r = 0; r < 4; r++) {
        int row = row0 + r, idx = row * 256 + colg;
        float dI = (row == colg) ? 1.0f : 0.0f;
        float xm = rdm(iXM, idx), u2 = rdm(iU2, idx);
        float u3 = 2.0f * a3[r] - xm;
        wrm(iU4, idx, 2.0f * a4[r] - dI);
        wrm(iCBA, idx, aM[8] * dI + aM[9] * xm + aM[10] * u2 + aM[11] * u3);
        wrm(iQM1, idx, aM[4] * dI + aM[5] * xm + aM[6] * u2 + aM[7] * u3);
        wrm(iQM0, idx, aM[0] * dI + aM[1] * xm + aM[2] * u2 + aM[3] * u3);
      }
    }
    gridbar(bid, &s_gen);
    { // r3: CBB = 2*U4*CBA + Q1
      f32x4 a = mmbf(iU4, iCBA, arow, colg, kq);
#pragma unroll
      for (int r = 0; r < 4; r++) {
        int idx = (row0 + r) * 256 + colg;
        wrm(iCBB, idx, 2.0f * a[r] + rdm(iQM1, idx));
      }
    }
    gridbar(bid, &s_gen);
    { // r4: ISQ = U4*CBB - CBA + Q0
      f32x4 a = mmbf(iU4, iCBB, arow, colg, kq);
#pragma unroll
      for (int r = 0; r < 4; r++) {
        int idx = (row0 + r) * 256 + colg;
        wrm(iISQ, idx, a[r] - rdm(iCBA, idx) + rdm(iQM0, idx));
      }
    }
    gridbar(bid, &s_gen);
    { // r5: SQ = (1/sM)*XM*ISQ + cM*ISQ ; G = ISQ*fk
      f32x4 a = mmbf(iXM, iISQ, arow, colg, kq);
      f32x4 b = mmbf_fB(iISQ, fk, arow, colg, kq);
#pragma unroll
      for (int r = 0; r < 4; r++) {
        int idx = (row0 + r) * 256 + colg;
        wrm(iSQ, idx, a[r] * (1.0f / sM) + cM * rdm(iISQ, idx));
        wrm(iG, idx, b[r]);
      }
    }
    gridbar(bid, &s_gen);
    { // r6: XS = sS*(G*ISQ) - sS*cS*I
      f32x4 a = mmbf(iG, iISQ, arow, colg, kq);
#pragma unroll
      for (int r = 0; r < 4; r++) {
        int row = row0 + r, idx = row * 256 + colg;
        wrm(iXS, idx, sS * a[r] - sS * cS * ((row == colg) ? 1.0f : 0.0f));
      }
    }
    gridbar(bid, &s_gen);

    // ---- P = p(S) ~ S^t: s=8, m=4, deg 39 ----
    { // r7: V2 = 2*XS*XS - I
      f32x4 a = mmbf(iXS, iXS, arow, colg, kq);
#pragma unroll
      for (int r = 0; r < 4; r++) {
        int row = row0 + r, idx = row * 256 + colg;
        wrm(iV2, idx, 2.0f * a[r] - ((row == colg) ? 1.0f : 0.0f));
      }
    }
    gridbar(bid, &s_gen);
    { // r8: V3 = 2*XS*V2 - XS ; V4 = 2*V2*V2 - I
      f32x4 a = mmbf(iXS, iV2, arow, colg, kq);
      f32x4 b = mmbf(iV2, iV2, arow, colg, kq);
#pragma unroll
      for (int r = 0; r < 4; r++) {
        int row = row0 + r, idx = row * 256 + colg;
        float dI = (row == colg) ? 1.0f : 0.0f;
        wrm(iV3, idx, 2.0f * a[r] - rdm(iXS, idx));
        wrm(iV4, idx, 2.0f * b[r] - dI);
      }
    }
    gridbar(bid, &s_gen);
    { // r9: V5..V7 (regs), V8 ; precompute q4 (SBA) and Q3..Q0 combos
      f32x4 a5 = mmbf(iV2, iV3, arow, colg, kq);
      f32x4 a6 = mmbf(iV3, iV3, arow, colg, kq);
      f32x4 a7 = mmbf(iV3, iV4, arow, colg, kq);
      f32x4 a8 = mmbf(iV4, iV4, arow, colg, kq);
#pragma unroll
      for (int r = 0; r < 4; r++) {
        int row = row0 + r, idx = row * 256 + colg;
        float dI = (row == colg) ? 1.0f : 0.0f;
        float xs = rdm(iXS, idx), v2 = rdm(iV2, idx), v3 = rdm(iV3, idx), v4 = rdm(iV4, idx);
        float v5 = 2.0f * a5[r] - xs;   // T5 = 2*T2*T3 - T1
        float v6 = 2.0f * a6[r] - dI;   // T6 = 2*T3*T3 - T0
        float v7 = 2.0f * a7[r] - xs;   // T7 = 2*T3*T4 - T1
        float v8 = 2.0f * a8[r] - dI;   // T8 = 2*T4*T4 - T0
        wrm(iV8, idx, v8);
        wrm(iSBA, idx, aS[32] * dI + aS[33] * xs + aS[34] * v2 + aS[35] * v3 +
                       aS[36] * v4 + aS[37] * v5 + aS[38] * v6 + aS[39] * v7);
        wrm(iQS3, idx, aS[24] * dI + aS[25] * xs + aS[26] * v2 + aS[27] * v3 +
                       aS[28] * v4 + aS[29] * v5 + aS[30] * v6 + aS[31] * v7);
        wrm(iQS2, idx, aS[16] * dI + aS[17] * xs + aS[18] * v2 + aS[19] * v3 +
                       aS[20] * v4 + aS[21] * v5 + aS[22] * v6 + aS[23] * v7);
        wrm(iQS1, idx, aS[8] * dI + aS[9] * xs + aS[10] * v2 + aS[11] * v3 +
                       aS[12] * v4 + aS[13] * v5 + aS[14] * v6 + aS[15] * v7);
        wrm(iQS0, idx, aS[0] * dI + aS[1] * xs + aS[2] * v2 + aS[3] * v3 +
                       aS[4] * v4 + aS[5] * v5 + aS[6] * v6 + aS[7] * v7);
      }
    }
    gridbar(bid, &s_gen);
    { // r10: b3 = 2*V8*b4 + Q3
      f32x4 a = mmbf(iV8, iSBA, arow, colg, kq);
#pragma unroll
      for (int r = 0; r < 4; r++) {
        int idx = (row0 + r) * 256 + colg;
        wrm(iSBB, idx, 2.0f * a[r] + rdm(iQS3, idx));
      }
    }
    gridbar(bid, &s_gen);
    { // r11: b2 = 2*V8*b3 - b4 + Q2
      f32x4 a = mmbf(iV8, iSBB, arow, colg, kq);
#pragma unroll
      for (int r = 0; r < 4; r++) {
        int idx = (row0 + r) * 256 + colg;
        wrm(iSBC, idx, 2.0f * a[r] - rdm(iSBA, idx) + rdm(iQS2, idx));
      }
    }
    gridbar(bid, &s_gen);
    { // r12: b1 = 2*V8*b2 - b3 + Q1
      f32x4 a = mmbf(iV8, iSBC, arow, colg, kq);
#pragma unroll
      for (int r = 0; r < 4; r++) {
        int idx = (row0 + r) * 256 + colg;
        wrm(iSBA, idx, 2.0f * a[r] - rdm(iSBB, idx) + rdm(iQS1, idx));
      }
    }
    gridbar(bid, &s_gen);
    { // r13: P = V8*b1 - b2 + Q0
      f32x4 a = mmbf(iV8, iSBA, arow, colg, kq);
#pragma unroll
      for (int r = 0; r < 4; r++) {
        int idx = (row0 + r) * 256 + colg;
        wrm(iPP, idx, a[r] - rdm(iSBC, idx) + rdm(iQS0, idx));
      }
    }
    gridbar(bid, &s_gen);
    { // r14: HH = SQ*P
      f32x4 a = mmbf(iSQ, iPP, arow, colg, kq);
#pragma unroll
      for (int r = 0; r < 4; r++) {
        int idx = (row0 + r) * 256 + colg;
        wrm(iHH, idx, a[r]);
      }
    }
    gridbar(bid, &s_gen);
    { // r15: Mn = HH*SQ -> out[k] (fp32); XM_next = sM*(Mn - cM*I)
      f32x4 a = mmbf(iHH, iSQ, arow, colg, kq);
      float* ok = out + (size_t)k * 65536;
#pragma unroll
      for (int r = 0; r < 4; r++) {
        int row = row0 + r, idx = row * 256 + colg;
        float dI = (row == colg) ? 1.0f : 0.0f;
        float v = a[r];
        ok[idx] = v;
        wrm(iXM, idx, sM * (v - cM * dI));
      }
    }
    gridbar(bid, &s_gen);
  }
}

extern "C" void kernel_launch(void* const* d_in, const int* in_sizes, int n_in,
                              void* d_out, int out_size, void* d_ws, size_t ws_size,
                              hipStream_t stream) {
  (void)in_sizes; (void)n_in; (void)d_ws; (void)ws_size; (void)out_size;
  const float* f = (const float*)d_in[0];
  const float* w = (const float*)d_in[1];
  float* out = (float*)d_out;

  setup_kernel<<<dim3(257), dim3(64), 0, stream>>>(w);

  // Plain (non-cooperative) launch: 64 blocks x 256 threads on 256 CUs is
  // trivially co-resident, so the hand-rolled agent-scope barrier is safe.
  frechet_kernel<<<dim3(NBLK), dim3(256), 0, stream>>>(f, out);
}